// Round 12
// baseline (380.213 us; speedup 1.0000x reference)
//
#include <hip/hip_runtime.h>
#include <hip/hip_cooperative_groups.h>
#include <math.h>

namespace cg = cooperative_groups;

#define N_NODES 20000
#define N_EDGES 40000
#define SE 46
#define TE 82
#define NB2 80        // virtual 256-thread node blocks (ceil(20000/256))
#define TT  131072    // total threads = 256 blocks * 512

typedef short  s16x8 __attribute__((ext_vector_type(8)));
typedef short  s16x4 __attribute__((ext_vector_type(4)));
typedef float  f32x4 __attribute__((ext_vector_type(4)));

__device__ __forceinline__ float sigf(float x){ return 1.0f/(1.0f+__expf(-x)); }
__device__ __forceinline__ float tanh_f(float x){ return 1.0f - 2.0f/(__expf(2.0f*x)+1.0f); }
__device__ __forceinline__ int perm_out(int i){ return (i&3)*128 + (i>>2); }
__device__ __forceinline__ unsigned short f2bf(float f){
  unsigned u = __builtin_bit_cast(unsigned, f);
  unsigned r = (u + 0x7fff + ((u>>16)&1)) >> 16;
  return (unsigned short)r;
}
__device__ __forceinline__ float bf2f(short s){
  unsigned u = ((unsigned)(unsigned short)s) << 16;
  return __builtin_bit_cast(float, u);
}
__device__ __forceinline__ int mapbin(int s){
  int p = s / (63*NB2);
  int r = s - p*(63*NB2);
  int li = r / NB2;
  int b  = r - li*NB2;
  int l  = 63 - li;
  return (p*64 + l)*NB2 + b;
}

struct MegaParams {
  const int *heads, *rels, *tails;
  const float *weeks, *ent, *rel_embs, *wfreq, *wphi, *wamp;
  const int *esrc, *edst;
  const float *x, *Wih, *Whh, *fc1w, *bih, *bhh, *fc1b, *lng, *lnb, *outw, *outb;
  float *out;
  short *scores, *WihB, *WhhB2, *fc1wbf, *pre2b;
  float *emb;
  int *sstart, *dstart, *scnt, *dcnt, *dc2, *nchains, *ctr;
  int *bhist, *boff, *dlist, *cnode, *cstart, *clen, *degf;
};

__global__ __launch_bounds__(512, 2) void k_mega(MegaParams P){
  __shared__ char SM[41472];
  cg::grid_group grid = cg::this_grid();
  int tid = threadIdx.x, blk = blockIdx.x;
  int gid = blk*512 + tid;

  // ================= P0: gather | weight prep | degree hist =================
  for (int c = gid; c < N_EDGES*16; c += TT){
    int e = c >> 4, d0 = (c & 15) << 3;
    int hd = P.heads[e], tl = P.tails[e], rl = P.rels[e];
    float wk = P.weeks[e];
    float hv[8], tv[8];
    if (d0 + 8 <= SE){
      const float* hp = P.ent + (size_t)hd*SE + d0;
      const float* tp = P.ent + (size_t)tl*SE + d0;
      #pragma unroll
      for (int j=0;j<4;j++){
        float2 a = *(const float2*)(hp + j*2); hv[2*j]=a.x; hv[2*j+1]=a.y;
        float2 b = *(const float2*)(tp + j*2); tv[2*j]=b.x; tv[2*j+1]=b.y;
      }
    } else if (d0 >= 48){
      int dt = d0 - SE;
      const float *hf = P.wfreq + (size_t)hd*TE + dt, *hp2 = P.wphi + (size_t)hd*TE + dt, *ha = P.wamp + (size_t)hd*TE + dt;
      const float *tf = P.wfreq + (size_t)tl*TE + dt, *tp2 = P.wphi + (size_t)tl*TE + dt, *ta = P.wamp + (size_t)tl*TE + dt;
      #pragma unroll
      for (int j=0;j<4;j++){
        float2 f_h = *(const float2*)(hf + j*2);
        float2 p_h = *(const float2*)(hp2 + j*2);
        float2 a_h = *(const float2*)(ha + j*2);
        float2 f_t = *(const float2*)(tf + j*2);
        float2 p_t = *(const float2*)(tp2 + j*2);
        float2 a_t = *(const float2*)(ta + j*2);
        hv[2*j]   = a_h.x*__sinf(f_h.x*wk + p_h.x);
        hv[2*j+1] = a_h.y*__sinf(f_h.y*wk + p_h.y);
        tv[2*j]   = a_t.x*__sinf(f_t.x*wk + p_t.x);
        tv[2*j+1] = a_t.y*__sinf(f_t.y*wk + p_t.y);
      }
    } else {
      #pragma unroll
      for (int j=0;j<8;j++){
        int d = 40 + j;
        if (d < SE){
          hv[j] = P.ent[(size_t)hd*SE + d];
          tv[j] = P.ent[(size_t)tl*SE + d];
        } else {
          int dt = d - SE;
          hv[j] = P.wamp[(size_t)hd*TE+dt]*__sinf(P.wfreq[(size_t)hd*TE+dt]*wk + P.wphi[(size_t)hd*TE+dt]);
          tv[j] = P.wamp[(size_t)tl*TE+dt]*__sinf(P.wfreq[(size_t)tl*TE+dt]*wk + P.wphi[(size_t)tl*TE+dt]);
        }
      }
    }
    const float* rp = P.rel_embs + rl*128 + d0;
    float4 r0 = *(const float4*)rp, r1 = *(const float4*)(rp+4);
    float rv[8] = {r0.x,r0.y,r0.z,r0.w, r1.x,r1.y,r1.z,r1.w};
    s16x8 o;
    #pragma unroll
    for (int j=0;j<8;j++) o[j] = (short)f2bf(hv[j]*rv[j]*tv[j]);
    *(s16x8*)(P.scores + (size_t)e*128 + d0) = o;
  }
  for (int i = gid; i < 180224; i += TT){
    if (i < 65536){
      int r = i >> 7, k = i & 127;
      P.WihB[i] = (short)f2bf(P.Wih[perm_out(r)*128 + k]);
    } else if (i < 131072){
      int j = i - 65536;
      P.WhhB2[j] = (short)f2bf(P.Whh[j]);
    } else {
      int j = i - 131072;
      P.fc1wbf[j] = (short)f2bf(P.fc1w[j]);
    }
  }
  if (gid < N_EDGES){ atomicAdd(&P.scnt[P.esrc[gid]],1); atomicAdd(&P.dcnt[P.edst[gid]],1); }
  grid.sync();

  // ================= P1: scan (blk 0) | pregemm (blks 1..255) =================
  if (blk == 0){
    int half = tid >> 8, t = tid & 255;
    const int* cnt = half ? P.dcnt : P.scnt;
    int* start = half ? P.dstart : P.sstart;
    int base = t*79;
    int lim = min(base+79, N_NODES);
    int tsum = 0;
    for (int i=base;i<lim;i++) tsum += cnt[i];
    int lane = tid & 63;
    int wv4 = t >> 6;
    int incl = tsum;
    #pragma unroll
    for (int m=1;m<64;m<<=1){ int u = __shfl_up(incl, m); if (lane >= m) incl += u; }
    int* wsA = (int*)SM;
    if (lane == 63) wsA[half*4 + wv4] = incl;
    __syncthreads();
    int woff = 0;
    for (int k=0;k<wv4;k++) woff += wsA[half*4 + k];
    int run = woff + incl - tsum;
    for (int i=base;i<lim;i++){ start[i] = run; run += cnt[i]; }
    if (t == 255) start[N_NODES] = run;
  } else {
    int half = tid >> 8, t = tid & 255;
    char* As = SM + half*8192;
    for (int rnd=0; rnd<3; rnd++){
      int tile = rnd*510 + (blk-1)*2 + half;
      bool act = (tile < 1250);
      int e0 = tile*32;
      if (act){
        #pragma unroll
        for (int q=0;q<2;q++){
          int c = t + 256*q;
          int el = c >> 4, k8 = c & 15;
          s16x8 v = *(const s16x8*)(P.scores + (size_t)(e0+el)*128 + k8*8);
          *(s16x8*)(As + ((el*256 + k8*16) ^ ((el&7)<<4))) = v;
        }
      }
      __syncthreads();
      if (act){
        int lane = t & 63, w = t >> 6;
        int cl = lane & 15, kq = lane >> 4;
        s16x8 a[2][4];
        #pragma unroll
        for (int ks=0;ks<4;ks++){
          int kb = ks*64 + kq*16;
          a[0][ks] = *(const s16x8*)(As + (((cl   )*256 + kb) ^ ((cl&7)<<4)));
          a[1][ks] = *(const s16x8*)(As + (((cl+16)*256 + kb) ^ (((cl+16)&7)<<4)));
        }
        f32x4 D[2][8];
        #pragma unroll
        for (int m=0;m<2;m++)
          #pragma unroll
          for (int i=0;i<8;i++) D[m][i] = (f32x4){0.f,0.f,0.f,0.f};
        #pragma unroll
        for (int i=0;i<8;i++){
          int n = w*128 + i*16 + cl;
          const short* bp = P.WihB + (size_t)n*128 + kq*8;
          #pragma unroll
          for (int ks=0;ks<4;ks++){
            s16x8 b = *(const s16x8*)(bp + ks*32);
            D[0][i] = __builtin_amdgcn_mfma_f32_16x16x32_bf16(a[0][ks], b, D[0][i], 0, 0, 0);
            D[1][i] = __builtin_amdgcn_mfma_f32_16x16x32_bf16(a[1][ks], b, D[1][i], 0, 0, 0);
          }
        }
        #pragma unroll
        for (int i=0;i<8;i++){
          int n = w*128 + i*16 + cl;
          int pn = perm_out(n);
          float bb = P.bih[pn] + P.bhh[pn];
          #pragma unroll
          for (int m=0;m<2;m++){
            #pragma unroll
            for (int q2=0;q2<4;q2++){
              int row = m*16 + kq*4 + q2;
              P.pre2b[(size_t)(e0+row)*512 + n] = (short)f2bf(D[m][i][q2] + bb);
            }
          }
        }
      }
      __syncthreads();
    }
  }
  grid.sync();

  // ================= P2: dst scatter | cbin1 + degf =================
  if (gid < N_EDGES){
    int d = P.edst[gid];
    int p2 = P.dstart[d] + atomicAdd(&P.dc2[d],1);
    P.dlist[p2] = gid;
  }
  if (blk < 40){
    int half = tid >> 8, t = tid & 255;
    int* h = (int*)SM + half*128;
    if (t < 128) h[t] = 0;
    __syncthreads();
    int vb = blk*2 + half;
    int n = vb*256 + t;
    if (n < N_NODES){
      int c0 = P.sstart[n+1]-P.sstart[n];
      int c1 = P.dstart[n+1]-P.dstart[n];
      P.degf[n] = (c0+c1 > 0) ? 1 : 0;
      if (c0>0 && c1==0) atomicAdd(&h[min(c0,63)], 1);
      if (c1>0) atomicAdd(&h[64+min(c1,63)], 1);
    }
    __syncthreads();
    if (t < 128) P.bhist[t*NB2 + vb] = h[t];
  }
  grid.sync();

  // ================= P3: sort dlist groups | cbin2 (blk 0) =================
  if (gid < N_NODES){
    int a = P.dstart[gid], b = P.dstart[gid+1];
    for (int i=a+1;i<b;i++){
      int v = P.dlist[i]; int j=i-1;
      while (j>=a && P.dlist[j]>v){ P.dlist[j+1]=P.dlist[j]; j--; }
      P.dlist[j+1]=v;
    }
  }
  if (blk == 0){
    const int S = 2*63*NB2;   // 10080
    const int CH2 = 20;       // 512*20 >= S
    int tsum = 0;
    for (int j=0;j<CH2;j++){
      int s = tid*CH2 + j;
      if (s < S) tsum += P.bhist[mapbin(s)];
    }
    int lane = tid & 63, wv = tid >> 6;
    int incl = tsum;
    #pragma unroll
    for (int m=1;m<64;m<<=1){ int u = __shfl_up(incl, m); if (lane >= m) incl += u; }
    int* ws = (int*)SM;
    int* pend = (int*)SM + 16;
    if (lane==63) ws[wv] = incl;
    __syncthreads();
    int woff = 0;
    for (int k=0;k<wv;k++) woff += ws[k];
    int run = woff + incl - tsum;
    for (int j=0;j<CH2;j++){
      int s = tid*CH2 + j;
      if (s < S){
        int bi = mapbin(s);
        int val = P.bhist[bi];
        P.boff[bi] = run;
        run += val;
        if (s == 63*NB2 - 1) pend[0] = run;
        if (s == S - 1)      pend[1] = run;
      }
    }
    __syncthreads();
    if (tid == 0){ P.nchains[0] = pend[0]; P.nchains[1] = pend[1] - pend[0]; }
  }
  grid.sync();

  // ================= P4: cbin3 chain compaction =================
  if (blk < 40){
    int half = tid >> 8, t = tid & 255;
    int* h = (int*)SM + half*128;
    if (t < 128) h[t] = 0;
    __syncthreads();
    int vb = blk*2 + half;
    int n = vb*256 + t;
    int bin0=-1, bin1=-1, r0=0, r1=0, a0=0, c0=0, a1=0, c1=0;
    if (n < N_NODES){
      a0 = P.sstart[n]; c0 = P.sstart[n+1]-a0;
      a1 = P.dstart[n]; c1 = P.dstart[n+1]-a1;
      if (c0>0 && c1==0){ bin0 = min(c0,63);    r0 = atomicAdd(&h[bin0],1); }
      if (c1>0)         { bin1 = 64+min(c1,63); r1 = atomicAdd(&h[bin1],1); }
    }
    __syncthreads();
    int nch0 = P.nchains[0];
    if (bin0 >= 0){
      int pos = P.boff[bin0*NB2 + vb] + r0;
      P.cnode[pos]=n; P.cstart[pos]=a0; P.clen[pos]=c0;
    }
    if (bin1 >= 0){
      int pos = P.boff[bin1*NB2 + vb] + r1 - nch0;
      P.cnode[N_NODES+pos]=n; P.cstart[N_NODES+pos]=a1; P.clen[N_NODES+pos]=c1;
    }
  }
  grid.sync();

  // ================= P5: persistent MFMA LSTM =================
  {
    char* Hb0 = SM;                      // [2][8192]
    int* M = (int*)(SM + 16384);         // [161]
    int lane = tid & 63, wv = tid >> 6;
    int cl = lane & 15, kq = lane >> 4;
    int d_own = wv*16 + cl;
    s16x8 wf[4][4];
    #pragma unroll
    for (int i=0;i<4;i++)
      #pragma unroll
      for (int ks=0;ks<4;ks++)
        wf[i][ks] = *(const s16x8*)(P.WhhB2 + (size_t)(i*128 + d_own)*128 + ks*32 + kq*8);
    int nch0 = P.nchains[0], nch1 = P.nchains[1];
    int B0 = (nch0+31)>>5, B1 = (nch1+31)>>5;
    while (true){
      if (tid==0) M[160] = atomicAdd(P.ctr, 1);
      __syncthreads();
      int nb = M[160];
      if (nb >= B0 + B1) break;
      int pass = (nb >= B0) ? 1 : 0;
      int batch = pass ? nb - B0 : nb;
      int b0 = batch << 5;
      int nch = pass ? nch1 : nch0;
      if (tid < 32){
        int j = b0 + tid;
        int valid = (j < nch);
        int ci = pass*N_NODES + j;
        int st = valid ? P.cstart[ci] : 0;
        int ln = valid ? P.clen[ci] : 0;
        M[tid] = ln; M[32+tid] = st; M[128+tid] = valid ? P.cnode[ci] : -1;
        M[64+tid] = (ln > 0) ? (pass ? P.dlist[st]   : st  ) : 0;
        M[96+tid] = (ln > 1) ? (pass ? P.dlist[st+1] : st+1) : 0;
      }
      *(unsigned long long*)(&Hb0[tid*16])   = 0ull;
      *(unsigned long long*)(&Hb0[tid*16+8]) = 0ull;
      float cst[8]  = {0.f,0.f,0.f,0.f,0.f,0.f,0.f,0.f};
      float hreg[8] = {0.f,0.f,0.f,0.f,0.f,0.f,0.f,0.f};
      __syncthreads();
      int mylen[8];
      #pragma unroll
      for (int m=0;m<2;m++)
        #pragma unroll
        for (int q=0;q<4;q++) mylen[m*4+q] = M[m*16 + kq*4 + q];
      int ml = 0;
      #pragma unroll 1
      for (int j=0;j<32;j++) ml = max(ml, M[j]);
      s16x4 pvc[8];
      #pragma unroll
      for (int m=0;m<2;m++)
        #pragma unroll
        for (int q=0;q<4;q++){
          int r = m*16 + kq*4 + q;
          pvc[m*4+q] = *(const s16x4*)(P.pre2b + (size_t)M[64+r]*512 + d_own*4);
        }
      __syncthreads();
      int cur = 0;
      for (int t=0; t<ml; t++){
        if (tid < 32){
          int ln = M[tid];
          int nxt = M[32+tid] + t + 2;
          M[64 + ((t&1)<<5) + tid] = (t+2 < ln) ? (pass ? P.dlist[nxt] : nxt) : 0;
        }
        s16x4 pvn[8];
        const int* eidN = M + 64 + (((t+1)&1)<<5);
        #pragma unroll
        for (int m=0;m<2;m++)
          #pragma unroll
          for (int q=0;q<4;q++){
            int r = m*16 + kq*4 + q;
            pvn[m*4+q] = *(const s16x4*)(P.pre2b + (size_t)eidN[r]*512 + d_own*4);
          }
        f32x4 D[2][4];
        #pragma unroll
        for (int m=0;m<2;m++)
          #pragma unroll
          for (int i=0;i<4;i++) D[m][i] = (f32x4){0.f,0.f,0.f,0.f};
        char* Hc = Hb0 + cur*8192;
        #pragma unroll
        for (int ks=0; ks<4; ks++){
          int kb = ks*64 + kq*16;
          s16x8 a0 = *(const s16x8*)(Hc + (((cl   )*256 + kb) ^ ((cl&7)<<4)));
          s16x8 a1 = *(const s16x8*)(Hc + (((cl+16)*256 + kb) ^ (((cl+16)&7)<<4)));
          #pragma unroll
          for (int i=0;i<4;i++){
            D[0][i] = __builtin_amdgcn_mfma_f32_16x16x32_bf16(a0, wf[i][ks], D[0][i], 0, 0, 0);
            D[1][i] = __builtin_amdgcn_mfma_f32_16x16x32_bf16(a1, wf[i][ks], D[1][i], 0, 0, 0);
          }
        }
        char* Hn = Hb0 + (cur^1)*8192;
        #pragma unroll
        for (int m=0;m<2;m++)
          #pragma unroll
          for (int q=0;q<4;q++){
            int r = m*16 + kq*4 + q;
            if (t < mylen[m*4+q]){
              s16x4 p = pvc[m*4+q];
              float gi = D[m][0][q] + bf2f(p[0]);
              float gf = D[m][1][q] + bf2f(p[1]);
              float gg = D[m][2][q] + bf2f(p[2]);
              float go = D[m][3][q] + bf2f(p[3]);
              int idx = m*4+q;
              cst[idx] = sigf(gf)*cst[idx] + sigf(gi)*tanh_f(gg);
              float h = sigf(go)*tanh_f(cst[idx]);
              hreg[idx] = h;
              *(short*)(Hn + ((r*256 + d_own*2) ^ ((r&7)<<4))) = (short)f2bf(h);
            }
          }
        __syncthreads();
        #pragma unroll
        for (int i=0;i<8;i++) pvc[i] = pvn[i];
        cur ^= 1;
      }
      #pragma unroll
      for (int m=0;m<2;m++)
        #pragma unroll
        for (int q=0;q<4;q++){
          int r = m*16 + kq*4 + q;
          int n = M[128+r];
          if (mylen[m*4+q] > 0 && n >= 0){
            P.emb[(size_t)n*128 + d_own] = hreg[m*4+q];
          }
        }
      __syncthreads();
    }
  }
  grid.sync();

  // ================= P6: MLP (625 tiles, 3 strided rounds) =================
  {
    char* As = SM;                                   // 24576 B
    float (*hbuf)[132] = (float(*)[132])(SM + 24576); // 16896 B
    int lane = tid & 63, w = tid >> 6;
    for (int rnd=0; rnd<3; rnd++){
      int tile = blk + 256*rnd;
      bool act = (tile < 625);
      int base = tile*32;
      if (act){
        #pragma unroll
        for (int q=0;q<3;q++){
          int i = tid + 512*q;
          int r = i / 48, c2 = i - r*48;
          s16x8 v8 = {0,0,0,0,0,0,0,0};
          if (c2 < 32){
            const float* src = P.x + (size_t)(base+r)*256 + c2*8;
            float4 v0 = *(const float4*)src;
            float4 v1 = *(const float4*)(src+4);
            v8[0]=(short)f2bf(v0.x); v8[1]=(short)f2bf(v0.y); v8[2]=(short)f2bf(v0.z); v8[3]=(short)f2bf(v0.w);
            v8[4]=(short)f2bf(v1.x); v8[5]=(short)f2bf(v1.y); v8[6]=(short)f2bf(v1.z); v8[7]=(short)f2bf(v1.w);
          } else if (P.degf[base+r]){
            const float* src = P.emb + (size_t)(base+r)*128 + (c2-32)*8;
            float4 v0 = *(const float4*)src;
            float4 v1 = *(const float4*)(src+4);
            v8[0]=(short)f2bf(v0.x); v8[1]=(short)f2bf(v0.y); v8[2]=(short)f2bf(v0.z); v8[3]=(short)f2bf(v0.w);
            v8[4]=(short)f2bf(v1.x); v8[5]=(short)f2bf(v1.y); v8[6]=(short)f2bf(v1.z); v8[7]=(short)f2bf(v1.w);
          }
          *(s16x8*)(As + ((r*768 + c2*16) ^ ((r&7)<<4))) = v8;
        }
      }
      __syncthreads();
      int cl = lane & 15, kq = lane >> 4;
      if (act){
        f32x4 D0 = {0.f,0.f,0.f,0.f}, D1 = {0.f,0.f,0.f,0.f};
        const short* bp = P.fc1wbf + (size_t)(w*16 + cl)*384 + kq*8;
        #pragma unroll
        for (int ks=0; ks<12; ks++){
          s16x8 b = *(const s16x8*)(bp + ks*32);
          int kb = ks*64 + kq*16;
          s16x8 a0 = *(const s16x8*)(As + (((cl   )*768 + kb) ^ ((cl&7)<<4)));
          s16x8 a1 = *(const s16x8*)(As + (((cl+16)*768 + kb) ^ (((cl+16)&7)<<4)));
          D0 = __builtin_amdgcn_mfma_f32_16x16x32_bf16(a0, b, D0, 0, 0, 0);
          D1 = __builtin_amdgcn_mfma_f32_16x16x32_bf16(a1, b, D1, 0, 0, 0);
        }
        int col = w*16 + cl;
        float bb = P.fc1b[col];
        #pragma unroll
        for (int q=0;q<4;q++){
          hbuf[kq*4+q][col]    = D0[q] + bb;
          hbuf[16+kq*4+q][col] = D1[q] + bb;
        }
      }
      __syncthreads();
      if (act){
        int sub = lane >> 4, l16 = lane & 15;
        int nd = w*4 + sub;
        float v[8];
        float s = 0.f;
        #pragma unroll
        for (int j=0;j<8;j++){ v[j] = hbuf[nd][l16*8+j]; s += v[j]; }
        #pragma unroll
        for (int m=1;m<16;m<<=1) s += __shfl_xor(s, m);
        float mu = s * (1.f/128.f);
        float va = 0.f;
        #pragma unroll
        for (int j=0;j<8;j++){ float dm = v[j]-mu; va += dm*dm; }
        #pragma unroll
        for (int m=1;m<16;m<<=1) va += __shfl_xor(va, m);
        float rstd = rsqrtf(va*(1.f/128.f) + 1e-5f);
        float o0=0.f, o1=0.f;
        #pragma unroll
        for (int j=0;j<8;j++){
          int c = l16*8+j;
          float h1 = (v[j]-mu)*rstd*P.lng[c] + P.lnb[c];
          h1 = fmaxf(h1, 0.f);
          o0 += h1*P.outw[c]; o1 += h1*P.outw[128+c];
        }
        #pragma unroll
        for (int m=1;m<16;m<<=1){ o0 += __shfl_xor(o0,m); o1 += __shfl_xor(o1,m); }
        if (l16==0){
          P.out[(size_t)(base+nd)*2]   = o0 + P.outb[0];
          P.out[(size_t)(base+nd)*2+1] = o1 + P.outb[1];
        }
      }
      __syncthreads();
    }
  }
}

extern "C" void kernel_launch(void* const* d_in, const int* in_sizes, int n_in,
                              void* d_out, int out_size, void* d_ws, size_t ws_size,
                              hipStream_t stream){
  char* ws = (char*)d_ws;
  size_t off = 0;
  auto alloc = [&](size_t bytes){ void* p = ws + off; off += (bytes + 255) & ~(size_t)255; return p; };
  short* pre2b  = (short*)alloc((size_t)N_EDGES*512*2);
  short* scores = (short*)alloc((size_t)N_EDGES*128*2);
  short* WihB   = (short*)alloc(512*128*2);
  short* WhhB2  = (short*)alloc(512*128*2);
  short* fc1wbf = (short*)alloc(128*384*2);
  float* emb    = (float*)alloc((size_t)N_NODES*128*4);
  int* sstart   = (int*)alloc((N_NODES+1)*4);
  int* dstart   = (int*)alloc((N_NODES+1)*4);
  int* zreg     = (int*)alloc((size_t)(3*N_NODES + 3)*4);
  int* scnt = zreg, *dcnt = zreg+N_NODES, *dc2 = zreg+2*N_NODES;
  int* nchains  = zreg + 3*N_NODES;
  int* ctr      = nchains + 2;
  int* bhist    = (int*)alloc((size_t)128*NB2*4);
  int* boff     = (int*)alloc((size_t)128*NB2*4);
  int* dlist    = (int*)alloc(N_EDGES*4);
  int* cnode    = (int*)alloc((size_t)2*N_NODES*4);
  int* cstart   = (int*)alloc((size_t)2*N_NODES*4);
  int* clen     = (int*)alloc((size_t)2*N_NODES*4);
  int* degf     = (int*)alloc((size_t)N_NODES*4);

  hipMemsetAsync(zreg, 0, (size_t)(3*N_NODES + 3)*4, stream);

  MegaParams mp;
  mp.heads = (const int*)d_in[1];
  mp.rels  = (const int*)d_in[2];
  mp.tails = (const int*)d_in[3];
  mp.weeks = (const float*)d_in[4];
  mp.ent   = (const float*)d_in[10];
  mp.rel_embs = (const float*)d_in[11];
  mp.wfreq = (const float*)d_in[12];
  mp.wphi  = (const float*)d_in[13];
  mp.wamp  = (const float*)d_in[14];
  mp.esrc  = (const int*)d_in[5];
  mp.edst  = (const int*)d_in[6];
  mp.x     = (const float*)d_in[0];
  mp.Wih   = (const float*)d_in[15];
  mp.Whh   = (const float*)d_in[16];
  mp.fc1w  = (const float*)d_in[19];
  mp.bih   = (const float*)d_in[17];
  mp.bhh   = (const float*)d_in[18];
  mp.fc1b  = (const float*)d_in[20];
  mp.lng   = (const float*)d_in[21];
  mp.lnb   = (const float*)d_in[22];
  mp.outw  = (const float*)d_in[23];
  mp.outb  = (const float*)d_in[24];
  mp.out   = (float*)d_out;
  mp.scores = scores; mp.WihB = WihB; mp.WhhB2 = WhhB2; mp.fc1wbf = fc1wbf;
  mp.pre2b = pre2b; mp.emb = emb;
  mp.sstart = sstart; mp.dstart = dstart;
  mp.scnt = scnt; mp.dcnt = dcnt; mp.dc2 = dc2;
  mp.nchains = nchains; mp.ctr = ctr;
  mp.bhist = bhist; mp.boff = boff; mp.dlist = dlist;
  mp.cnode = cnode; mp.cstart = cstart; mp.clen = clen; mp.degf = degf;

  void* args[] = { &mp };
  hipLaunchCooperativeKernel((const void*)k_mega, dim3(256), dim3(512), args, 0, stream);
}

// Round 13
// 178.340 us; speedup vs baseline: 2.1320x; 2.1320x over previous
//
#include <hip/hip_runtime.h>
#include <math.h>

#define N_NODES 20000
#define N_EDGES 40000
#define SE 46
#define TE 82
#define NBLK 79   // ceil(N_NODES/256)
// D = 128, 4D = 512, F = 256, HID = 128

typedef short  s16x8 __attribute__((ext_vector_type(8)));
typedef short  s16x4 __attribute__((ext_vector_type(4)));
typedef float  f32x4 __attribute__((ext_vector_type(4)));

__device__ __forceinline__ float sigf(float x){ return 1.0f/(1.0f+__expf(-x)); }
__device__ __forceinline__ float tanh_f(float x){ return 1.0f - 2.0f/(__expf(2.0f*x)+1.0f); }
__device__ __forceinline__ int perm_out(int i){ return (i&3)*128 + (i>>2); }
__device__ __forceinline__ unsigned short f2bf(float f){
  unsigned u = __builtin_bit_cast(unsigned, f);
  unsigned r = (u + 0x7fff + ((u>>16)&1)) >> 16;
  return (unsigned short)r;
}
__device__ __forceinline__ float bf2f(short s){
  unsigned u = ((unsigned)(unsigned short)s) << 16;
  return __builtin_bit_cast(float, u);
}

#define GATHER_BLKS 2500
#define PREP_BLKS   704
#define HIST_BLKS   157
#define FRONT_BLKS  (GATHER_BLKS + PREP_BLKS + HIST_BLKS)

// ---------------- fused front: gather | weight-prep | hist ----------------
__global__ __launch_bounds__(256) void k_front(
    const int* __restrict__ heads, const int* __restrict__ rels,
    const int* __restrict__ tails, const float* __restrict__ weeks,
    const float* __restrict__ ent, const float* __restrict__ rel_embs,
    const float* __restrict__ wfreq, const float* __restrict__ wphi,
    const float* __restrict__ wamp, short* __restrict__ scores,
    const float* __restrict__ Wih, const float* __restrict__ Whh,
    const float* __restrict__ fc1w,
    short* __restrict__ WihB, short* __restrict__ WhhB2, short* __restrict__ fc1wbf,
    const int* __restrict__ esrc, const int* __restrict__ edst,
    int* __restrict__ scnt, int* __restrict__ dcnt){
  int blk = blockIdx.x, tid = threadIdx.x;
  if (blk < GATHER_BLKS){
    int c = blk*256 + tid;            // 640000 chunks
    int e = c >> 4, d0 = (c & 15) << 3;
    int hd = heads[e], tl = tails[e], rl = rels[e];
    float wk = weeks[e];
    float hv[8], tv[8];
    if (d0 + 8 <= SE){
      const float* hp = ent + (size_t)hd*SE + d0;
      const float* tp = ent + (size_t)tl*SE + d0;
      #pragma unroll
      for (int j=0;j<4;j++){
        float2 a = *(const float2*)(hp + j*2); hv[2*j]=a.x; hv[2*j+1]=a.y;
        float2 b = *(const float2*)(tp + j*2); tv[2*j]=b.x; tv[2*j+1]=b.y;
      }
    } else if (d0 >= 48){
      int dt = d0 - SE;
      const float *hf = wfreq + (size_t)hd*TE + dt, *hp2 = wphi + (size_t)hd*TE + dt, *ha = wamp + (size_t)hd*TE + dt;
      const float *tf = wfreq + (size_t)tl*TE + dt, *tp2 = wphi + (size_t)tl*TE + dt, *ta = wamp + (size_t)tl*TE + dt;
      #pragma unroll
      for (int j=0;j<4;j++){
        float2 f_h = *(const float2*)(hf + j*2);
        float2 p_h = *(const float2*)(hp2 + j*2);
        float2 a_h = *(const float2*)(ha + j*2);
        float2 f_t = *(const float2*)(tf + j*2);
        float2 p_t = *(const float2*)(tp2 + j*2);
        float2 a_t = *(const float2*)(ta + j*2);
        hv[2*j]   = a_h.x*__sinf(f_h.x*wk + p_h.x);
        hv[2*j+1] = a_h.y*__sinf(f_h.y*wk + p_h.y);
        tv[2*j]   = a_t.x*__sinf(f_t.x*wk + p_t.x);
        tv[2*j+1] = a_t.y*__sinf(f_t.y*wk + p_t.y);
      }
    } else {
      #pragma unroll
      for (int j=0;j<8;j++){
        int d = 40 + j;
        if (d < SE){
          hv[j] = ent[(size_t)hd*SE + d];
          tv[j] = ent[(size_t)tl*SE + d];
        } else {
          int dt = d - SE;
          hv[j] = wamp[(size_t)hd*TE+dt]*__sinf(wfreq[(size_t)hd*TE+dt]*wk + wphi[(size_t)hd*TE+dt]);
          tv[j] = wamp[(size_t)tl*TE+dt]*__sinf(wfreq[(size_t)tl*TE+dt]*wk + wphi[(size_t)tl*TE+dt]);
        }
      }
    }
    const float* rp = rel_embs + rl*128 + d0;
    float4 r0 = *(const float4*)rp, r1 = *(const float4*)(rp+4);
    float rv[8] = {r0.x,r0.y,r0.z,r0.w, r1.x,r1.y,r1.z,r1.w};
    s16x8 o;
    #pragma unroll
    for (int j=0;j<8;j++) o[j] = (short)f2bf(hv[j]*rv[j]*tv[j]);
    *(s16x8*)(scores + (size_t)e*128 + d0) = o;
  } else if (blk < GATHER_BLKS + PREP_BLKS){
    int idx = (blk - GATHER_BLKS)*256 + tid;
    if (idx < 65536){
      int i = idx >> 7, k = idx & 127;
      WihB[idx] = (short)f2bf(Wih[perm_out(i)*128 + k]);
    } else if (idx < 131072){
      int j = idx - 65536;
      WhhB2[j] = (short)f2bf(Whh[j]);
    } else if (idx < 180224){
      int j = idx - 131072;
      fc1wbf[j] = (short)f2bf(fc1w[j]);
    }
  } else {
    int e = (blk - GATHER_BLKS - PREP_BLKS)*256 + tid;
    if (e < N_EDGES){ atomicAdd(&scnt[esrc[e]],1); atomicAdd(&dcnt[edst[e]],1); }
  }
}

// ---------------- fused: scan (blocks 0,1) | MFMA pregemm (blocks 2..1251) ----------------
__global__ __launch_bounds__(256) void k_pgscan(
    const short* __restrict__ scores, const short* __restrict__ WihB,
    const float* __restrict__ bih, const float* __restrict__ bhh,
    short* __restrict__ pre2b,
    const int* __restrict__ scnt, const int* __restrict__ dcnt,
    int* __restrict__ sstart, int* __restrict__ dstart){
  __shared__ char As[32*256];   // pregemm staging (also aliases nothing for scan path)
  __shared__ int wsA[4];
  int blk = blockIdx.x, tid = threadIdx.x;
  if (blk < 2){
    const int* cnt = blk ? dcnt : scnt;
    int* start = blk ? dstart : sstart;
    int base = tid*79;
    int lim = min(base+79, N_NODES);
    int tsum = 0;
    for (int i=base;i<lim;i++) tsum += cnt[i];
    int lane = tid & 63, wv4 = tid >> 6;
    int incl = tsum;
    #pragma unroll
    for (int m=1;m<64;m<<=1){ int u = __shfl_up(incl, m); if (lane >= m) incl += u; }
    if (lane == 63) wsA[wv4] = incl;
    __syncthreads();
    int woff = 0;
    for (int k=0;k<wv4;k++) woff += wsA[k];
    int run = woff + incl - tsum;
    for (int i=base;i<lim;i++){ start[i] = run; run += cnt[i]; }
    if (tid == 255) start[N_NODES] = run;
    return;
  }
  int e0 = (blk-2) * 32;
  #pragma unroll
  for (int q=0;q<2;q++){
    int c = tid + 256*q;            // 0..511
    int el = c >> 4, k8 = c & 15;
    s16x8 v = *(const s16x8*)(scores + (size_t)(e0+el)*128 + k8*8);
    *(s16x8*)(As + ((el*256 + k8*16) ^ ((el&7)<<4))) = v;
  }
  __syncthreads();
  int lane = tid & 63, w = tid >> 6;
  int cl = lane & 15, kq = lane >> 4;
  s16x8 a[2][4];
  #pragma unroll
  for (int ks=0;ks<4;ks++){
    int kb = ks*64 + kq*16;
    a[0][ks] = *(const s16x8*)(As + (((cl   )*256 + kb) ^ ((cl&7)<<4)));
    a[1][ks] = *(const s16x8*)(As + (((cl+16)*256 + kb) ^ (((cl+16)&7)<<4)));
  }
  f32x4 D[2][8];
  #pragma unroll
  for (int m=0;m<2;m++)
    #pragma unroll
    for (int i=0;i<8;i++) D[m][i] = (f32x4){0.f,0.f,0.f,0.f};
  #pragma unroll
  for (int i=0;i<8;i++){
    int n = w*128 + i*16 + cl;
    const short* bp = WihB + (size_t)n*128 + kq*8;
    #pragma unroll
    for (int ks=0;ks<4;ks++){
      s16x8 b = *(const s16x8*)(bp + ks*32);
      D[0][i] = __builtin_amdgcn_mfma_f32_16x16x32_bf16(a[0][ks], b, D[0][i], 0, 0, 0);
      D[1][i] = __builtin_amdgcn_mfma_f32_16x16x32_bf16(a[1][ks], b, D[1][i], 0, 0, 0);
    }
  }
  #pragma unroll
  for (int i=0;i<8;i++){
    int n = w*128 + i*16 + cl;
    int pn = perm_out(n);
    float bb = bih[pn] + bhh[pn];
    #pragma unroll
    for (int m=0;m<2;m++){
      #pragma unroll
      for (int q2=0;q2<4;q2++){
        int row = m*16 + kq*4 + q2;
        pre2b[(size_t)(e0+row)*512 + n] = (short)f2bf(D[m][i][q2] + bb);
      }
    }
  }
}

// ---------------- scatter (dst only; src list is identity) + cbin1 ----------------
__global__ __launch_bounds__(256) void k_scatcb1(
    const int* __restrict__ edst, const int* __restrict__ dstart,
    int* __restrict__ dc2, int* __restrict__ dlist,
    const int* __restrict__ sstart, int* __restrict__ bhist){
  int blk = blockIdx.x, tid = threadIdx.x;
  if (blk < HIST_BLKS){
    int e = blk*256 + tid;
    if (e < N_EDGES){
      int d = edst[e]; int p2 = dstart[d] + atomicAdd(&dc2[d],1); dlist[p2]=e;
    }
  } else {
    __shared__ int h[128];
    int b2 = blk - HIST_BLKS;
    if (tid < 128) h[tid] = 0;
    __syncthreads();
    int n = b2*256 + tid;
    if (n < N_NODES){
      int c  = sstart[n+1]-sstart[n];
      int c2 = dstart[n+1]-dstart[n];
      if (c>0 && c2==0) atomicAdd(&h[min(c,63)], 1);
      if (c2>0) atomicAdd(&h[64+min(c2,63)], 1);
    }
    __syncthreads();
    if (tid < 128) bhist[tid*NBLK + b2] = h[tid];
  }
}

__device__ __forceinline__ int mapbin(int s){
  int p = s / (63*NBLK);
  int r = s - p*(63*NBLK);
  int li = r / NBLK;
  int b  = r - li*NBLK;
  int l  = 63 - li;
  return (p*64 + l)*NBLK + b;
}

// ---------------- sort dlist groups + cbin2 (256-thread two-pass scan) ----------------
__global__ __launch_bounds__(256) void k_sortcb2(
    const int* __restrict__ dstart, int* __restrict__ dlist,
    const int* __restrict__ bhist, int* __restrict__ boff,
    int* __restrict__ nchains){
  int blk = blockIdx.x, tid = threadIdx.x;
  __shared__ int wsum[4];
  __shared__ int pend[2];
  if (blk < NBLK){
    int n = blk*256 + tid;
    if (n < N_NODES){
      int a = dstart[n], b = dstart[n+1];
      for (int i=a+1;i<b;i++){
        int v = dlist[i]; int j=i-1;
        while (j>=a && dlist[j]>v){ dlist[j+1]=dlist[j]; j--; }
        dlist[j+1]=v;
      }
    }
  } else {
    const int S = 2*63*NBLK;   // 9954
    const int CH2 = 39;        // 256*39 = 9984
    int tsum = 0;
    for (int j=0;j<CH2;j++){
      int s = tid*CH2 + j;
      if (s < S) tsum += bhist[mapbin(s)];
    }
    int lane = tid & 63, wv = tid >> 6;
    int incl = tsum;
    #pragma unroll
    for (int m=1;m<64;m<<=1){ int u = __shfl_up(incl, m); if (lane >= m) incl += u; }
    if (lane==63) wsum[wv] = incl;
    __syncthreads();
    int woff = 0;
    for (int k=0;k<wv;k++) woff += wsum[k];
    int run = woff + incl - tsum;
    for (int j=0;j<CH2;j++){
      int s = tid*CH2 + j;
      if (s < S){
        int bi = mapbin(s);
        int val = bhist[bi];
        boff[bi] = run;
        run += val;
        if (s == 63*NBLK - 1) pend[0] = run;
        if (s == S - 1)       pend[1] = run;
      }
    }
    __syncthreads();
    if (tid == 0){
      nchains[0] = pend[0];
      nchains[1] = pend[1] - pend[0];
    }
  }
}

// ---------------- cbin3: chain compaction + emb-valid flags ----------------
__global__ void k_cbin3(const int* __restrict__ sstart, const int* __restrict__ dstart,
                        const int* __restrict__ boff, const int* __restrict__ nchains,
                        int* __restrict__ cnode, int* __restrict__ cstart,
                        int* __restrict__ clen, int* __restrict__ degf){
  __shared__ int h[128];
  int tid = threadIdx.x, blk = blockIdx.x;
  if (tid < 128) h[tid] = 0;
  __syncthreads();
  int n = blk*256 + tid;
  int bin0=-1, bin1=-1, r0=0, r1=0, a0=0, c0=0, a1=0, c1=0;
  if (n < N_NODES){
    a0 = sstart[n]; c0 = sstart[n+1]-a0;
    a1 = dstart[n]; c1 = dstart[n+1]-a1;
    degf[n] = (c0+c1 > 0) ? 1 : 0;
    if (c0>0 && c1==0){ bin0 = min(c0,63);    r0 = atomicAdd(&h[bin0], 1); }
    if (c1>0)         { bin1 = 64+min(c1,63); r1 = atomicAdd(&h[bin1], 1); }
  }
  __syncthreads();
  int nch0 = nchains[0];
  if (bin0 >= 0){
    int pos = boff[bin0*NBLK + blk] + r0;
    cnode[pos] = n; cstart[pos] = a0; clen[pos] = c0;
  }
  if (bin1 >= 0){
    int pos = boff[bin1*NBLK + blk] + r1 - nch0;
    cnode[N_NODES+pos] = n; cstart[N_NODES+pos] = a1; clen[N_NODES+pos] = c1;
  }
}

// ---------------- persistent MFMA LSTM v7: Whh in registers, early eid prefetch ----------------
__global__ __launch_bounds__(512, 1) void k_lstm7(
    const short* __restrict__ pre2b, const short* __restrict__ WhhB2,
    const int* __restrict__ cnode, const int* __restrict__ cstart,
    const int* __restrict__ clen, const int* __restrict__ nchains,
    const int* __restrict__ dlist, int* __restrict__ ctr,
    float* __restrict__ emb){
  __shared__ char Hb[2][8192];
  __shared__ int M[161];
  int tid = threadIdx.x;
  int lane = tid & 63, wv = tid >> 6;
  int cl = lane & 15, kq = lane >> 4;
  int d_own = wv*16 + cl;
  s16x8 wf[4][4];
  #pragma unroll
  for (int i=0;i<4;i++)
    #pragma unroll
    for (int ks=0;ks<4;ks++)
      wf[i][ks] = *(const s16x8*)(WhhB2 + (size_t)(i*128 + d_own)*128 + ks*32 + kq*8);
  int nch0 = nchains[0], nch1 = nchains[1];
  int B0 = (nch0+31)>>5, B1 = (nch1+31)>>5;
  while (true){
    if (tid==0) M[160] = atomicAdd(ctr, 1);
    __syncthreads();
    int nb = M[160];
    if (nb >= B0 + B1) break;
    int pass = (nb >= B0) ? 1 : 0;
    int batch = pass ? nb - B0 : nb;
    int b0 = batch << 5;
    int nch = pass ? nch1 : nch0;
    if (tid < 32){
      int j = b0 + tid;
      int valid = (j < nch);
      int ci = pass*N_NODES + j;
      int st = valid ? cstart[ci] : 0;
      int ln = valid ? clen[ci] : 0;
      M[tid] = ln; M[32+tid] = st; M[128+tid] = valid ? cnode[ci] : -1;
      M[64+tid] = (ln > 0) ? (pass ? dlist[st]   : st  ) : 0;
      M[96+tid] = (ln > 1) ? (pass ? dlist[st+1] : st+1) : 0;
    }
    *(unsigned long long*)(&Hb[0][tid*16])   = 0ull;
    *(unsigned long long*)(&Hb[0][tid*16+8]) = 0ull;
    float cst[8]  = {0.f,0.f,0.f,0.f,0.f,0.f,0.f,0.f};
    float hreg[8] = {0.f,0.f,0.f,0.f,0.f,0.f,0.f,0.f};
    __syncthreads();
    int mylen[8];
    #pragma unroll
    for (int m=0;m<2;m++)
      #pragma unroll
      for (int q=0;q<4;q++) mylen[m*4+q] = M[m*16 + kq*4 + q];
    int ml = 0;
    #pragma unroll 1
    for (int j=0;j<32;j++) ml = max(ml, M[j]);
    // preload pv for t=0 (slot 0)
    s16x4 pvc[8];
    #pragma unroll
    for (int m=0;m<2;m++)
      #pragma unroll
      for (int q=0;q<4;q++){
        int r = m*16 + kq*4 + q;
        pvc[m*4+q] = *(const s16x4*)(pre2b + (size_t)M[64+r]*512 + d_own*4);
      }
    __syncthreads();   // protect slot 0 from t=0's early prefetch write
    int cur = 0;
    for (int t=0; t<ml; t++){
      // early eid prefetch for t+2 into slot (t&1) (overlaps MFMA below)
      if (tid < 32){
        int ln = M[tid];
        int nxt = M[32+tid] + t + 2;
        M[64 + ((t&1)<<5) + tid] = (t+2 < ln) ? (pass ? dlist[nxt] : nxt) : 0;
      }
      // issue pv loads for t+1 from slot ((t+1)&1)
      s16x4 pvn[8];
      const int* eidN = M + 64 + (((t+1)&1)<<5);
      #pragma unroll
      for (int m=0;m<2;m++)
        #pragma unroll
        for (int q=0;q<4;q++){
          int r = m*16 + kq*4 + q;
          pvn[m*4+q] = *(const s16x4*)(pre2b + (size_t)eidN[r]*512 + d_own*4);
        }
      // MFMA from H[cur] x wf (registers)
      f32x4 D[2][4];
      #pragma unroll
      for (int m=0;m<2;m++)
        #pragma unroll
        for (int i=0;i<4;i++) D[m][i] = (f32x4){0.f,0.f,0.f,0.f};
      char* Hc = Hb[cur];
      #pragma unroll
      for (int ks=0; ks<4; ks++){
        int kb = ks*64 + kq*16;
        s16x8 a0 = *(const s16x8*)(Hc + (((cl   )*256 + kb) ^ ((cl&7)<<4)));
        s16x8 a1 = *(const s16x8*)(Hc + (((cl+16)*256 + kb) ^ (((cl+16)&7)<<4)));
        #pragma unroll
        for (int i=0;i<4;i++){
          D[0][i] = __builtin_amdgcn_mfma_f32_16x16x32_bf16(a0, wf[i][ks], D[0][i], 0, 0, 0);
          D[1][i] = __builtin_amdgcn_mfma_f32_16x16x32_bf16(a1, wf[i][ks], D[1][i], 0, 0, 0);
        }
      }
      // gate combine with pvc; write h to H[cur^1]
      char* Hn = Hb[cur^1];
      #pragma unroll
      for (int m=0;m<2;m++)
        #pragma unroll
        for (int q=0;q<4;q++){
          int r = m*16 + kq*4 + q;
          if (t < mylen[m*4+q]){
            s16x4 p = pvc[m*4+q];
            float gi = D[m][0][q] + bf2f(p[0]);
            float gf = D[m][1][q] + bf2f(p[1]);
            float gg = D[m][2][q] + bf2f(p[2]);
            float go = D[m][3][q] + bf2f(p[3]);
            int idx = m*4+q;
            cst[idx] = sigf(gf)*cst[idx] + sigf(gi)*tanh_f(gg);
            float h = sigf(go)*tanh_f(cst[idx]);
            hreg[idx] = h;
            *(short*)(Hn + ((r*256 + d_own*2) ^ ((r&7)<<4))) = (short)f2bf(h);
          }
        }
      __syncthreads();
      #pragma unroll
      for (int i=0;i<8;i++) pvc[i] = pvn[i];
      cur ^= 1;
    }
    #pragma unroll
    for (int m=0;m<2;m++)
      #pragma unroll
      for (int q=0;q<4;q++){
        int r = m*16 + kq*4 + q;
        int n = M[128+r];
        if (mylen[m*4+q] > 0 && n >= 0){
          emb[(size_t)n*128 + d_own] = hreg[m*4+q];
        }
      }
    __syncthreads();
  }
}

// ---------------- MFMA MLP: 32 nodes/block, degf-gated emb read ----------------
__global__ __launch_bounds__(512) void k_mlp2(
    const float* __restrict__ x, const float* __restrict__ emb,
    const int* __restrict__ degf,
    const short* __restrict__ fc1wbf, const float* __restrict__ fc1b,
    const float* __restrict__ lng, const float* __restrict__ lnb,
    const float* __restrict__ outw, const float* __restrict__ outb,
    float* __restrict__ out){
  __shared__ char As[32*768];          // bf16 [32][384], XOR-swizzled rows
  __shared__ float hbuf[32][132];
  int tid = threadIdx.x;
  int lane = tid & 63, w = tid >> 6;
  int base = blockIdx.x * 32;
  #pragma unroll
  for (int q=0;q<3;q++){
    int i = tid + 512*q;              // 0..1535, 48 chunks of 8 per row
    int r = i / 48, c = i - r*48;
    s16x8 v8 = {0,0,0,0,0,0,0,0};
    if (c < 32){
      const float* src = x + (size_t)(base+r)*256 + c*8;
      float4 v0 = *(const float4*)src;
      float4 v1 = *(const float4*)(src+4);
      v8[0]=(short)f2bf(v0.x); v8[1]=(short)f2bf(v0.y); v8[2]=(short)f2bf(v0.z); v8[3]=(short)f2bf(v0.w);
      v8[4]=(short)f2bf(v1.x); v8[5]=(short)f2bf(v1.y); v8[6]=(short)f2bf(v1.z); v8[7]=(short)f2bf(v1.w);
    } else if (degf[base+r]){
      const float* src = emb + (size_t)(base+r)*128 + (c-32)*8;
      float4 v0 = *(const float4*)src;
      float4 v1 = *(const float4*)(src+4);
      v8[0]=(short)f2bf(v0.x); v8[1]=(short)f2bf(v0.y); v8[2]=(short)f2bf(v0.z); v8[3]=(short)f2bf(v0.w);
      v8[4]=(short)f2bf(v1.x); v8[5]=(short)f2bf(v1.y); v8[6]=(short)f2bf(v1.z); v8[7]=(short)f2bf(v1.w);
    }
    *(s16x8*)(As + ((r*768 + c*16) ^ ((r&7)<<4))) = v8;
  }
  __syncthreads();
  int cl = lane & 15, kq = lane >> 4;
  f32x4 D0 = {0.f,0.f,0.f,0.f}, D1 = {0.f,0.f,0.f,0.f};
  const short* bp = fc1wbf + (size_t)(w*16 + cl)*384 + kq*8;
  #pragma unroll
  for (int ks=0; ks<12; ks++){
    s16x8 b = *(const s16x8*)(bp + ks*32);
    int kb = ks*64 + kq*16;
    s16x8 a0 = *(const s16x8*)(As + (((cl   )*768 + kb) ^ ((cl&7)<<4)));
    s16x8 a1 = *(const s16x8*)(As + (((cl+16)*768 + kb) ^ (((cl+16)&7)<<4)));
    D0 = __builtin_amdgcn_mfma_f32_16x16x32_bf16(a0, b, D0, 0, 0, 0);
    D1 = __builtin_amdgcn_mfma_f32_16x16x32_bf16(a1, b, D1, 0, 0, 0);
  }
  int col = w*16 + cl;
  float bb = fc1b[col];
  #pragma unroll
  for (int q=0;q<4;q++){
    hbuf[kq*4+q][col]    = D0[q] + bb;
    hbuf[16+kq*4+q][col] = D1[q] + bb;
  }
  __syncthreads();
  int sub = lane >> 4, l16 = lane & 15;
  int nd = w*4 + sub;
  float v[8];
  float s = 0.f;
  #pragma unroll
  for (int j=0;j<8;j++){ v[j] = hbuf[nd][l16*8+j]; s += v[j]; }
  #pragma unroll
  for (int m=1;m<16;m<<=1) s += __shfl_xor(s, m);
  float mu = s * (1.f/128.f);
  float va = 0.f;
  #pragma unroll
  for (int j=0;j<8;j++){ float dm = v[j]-mu; va += dm*dm; }
  #pragma unroll
  for (int m=1;m<16;m<<=1) va += __shfl_xor(va, m);
  float rstd = rsqrtf(va*(1.f/128.f) + 1e-5f);
  float o0=0.f, o1=0.f;
  #pragma unroll
  for (int j=0;j<8;j++){
    int c = l16*8+j;
    float h1 = (v[j]-mu)*rstd*lng[c] + lnb[c];
    h1 = fmaxf(h1, 0.f);
    o0 += h1*outw[c]; o1 += h1*outw[128+c];
  }
  #pragma unroll
  for (int m=1;m<16;m<<=1){ o0 += __shfl_xor(o0,m); o1 += __shfl_xor(o1,m); }
  if (l16==0){
    out[(size_t)(base+nd)*2]   = o0 + outb[0];
    out[(size_t)(base+nd)*2+1] = o1 + outb[1];
  }
}

extern "C" void kernel_launch(void* const* d_in, const int* in_sizes, int n_in,
                              void* d_out, int out_size, void* d_ws, size_t ws_size,
                              hipStream_t stream){
  const float* x      = (const float*)d_in[0];
  const int*   heads  = (const int*)d_in[1];
  const int*   rels   = (const int*)d_in[2];
  const int*   tails  = (const int*)d_in[3];
  const float* weeks  = (const float*)d_in[4];
  const int*   esrc   = (const int*)d_in[5];
  const int*   edst   = (const int*)d_in[6];
  const float* ent    = (const float*)d_in[10];
  const float* rel_e  = (const float*)d_in[11];
  const float* wfreq  = (const float*)d_in[12];
  const float* wphi   = (const float*)d_in[13];
  const float* wamp   = (const float*)d_in[14];
  const float* Wih    = (const float*)d_in[15];
  const float* Whh    = (const float*)d_in[16];
  const float* bih    = (const float*)d_in[17];
  const float* bhh    = (const float*)d_in[18];
  const float* fc1w   = (const float*)d_in[19];
  const float* fc1b   = (const float*)d_in[20];
  const float* lng    = (const float*)d_in[21];
  const float* lnb    = (const float*)d_in[22];
  const float* outw   = (const float*)d_in[23];
  const float* outb   = (const float*)d_in[24];
  float* out = (float*)d_out;

  char* ws = (char*)d_ws;
  size_t off = 0;
  auto alloc = [&](size_t bytes){ void* p = ws + off; off += (bytes + 255) & ~(size_t)255; return p; };
  short* pre2b  = (short*)alloc((size_t)N_EDGES*512*2);
  short* scores = (short*)alloc((size_t)N_EDGES*128*2);
  short* WihB   = (short*)alloc(512*128*2);
  short* WhhB2  = (short*)alloc(512*128*2);
  short* fc1wbf = (short*)alloc(128*384*2);
  float* emb    = (float*)alloc((size_t)N_NODES*128*4);
  int* sstart   = (int*)alloc((N_NODES+1)*4);
  int* dstart   = (int*)alloc((N_NODES+1)*4);
  int* zreg     = (int*)alloc((size_t)(3*N_NODES + 3)*4);
  int* scnt = zreg, *dcnt = zreg+N_NODES, *dc2 = zreg+2*N_NODES;
  int* nchains  = zreg + 3*N_NODES;
  int* ctr      = nchains + 2;
  int* bhist    = (int*)alloc((size_t)128*NBLK*4);
  int* boff     = (int*)alloc((size_t)128*NBLK*4);
  int* dlist    = (int*)alloc(N_EDGES*4);
  int* cnode    = (int*)alloc((size_t)2*N_NODES*4);
  int* cstart   = (int*)alloc((size_t)2*N_NODES*4);
  int* clen     = (int*)alloc((size_t)2*N_NODES*4);
  int* degf     = (int*)alloc((size_t)N_NODES*4);

  hipMemsetAsync(zreg, 0, (size_t)(3*N_NODES + 3)*4, stream);

  k_front<<<FRONT_BLKS, 256, 0, stream>>>(heads, rels, tails, weeks, ent, rel_e,
                                          wfreq, wphi, wamp, scores,
                                          Wih, Whh, fc1w, WihB, WhhB2, fc1wbf,
                                          esrc, edst, scnt, dcnt);
  k_pgscan<<<2 + N_EDGES/32, 256, 0, stream>>>(scores, WihB, bih, bhh, pre2b,
                                               scnt, dcnt, sstart, dstart);
  k_scatcb1<<<HIST_BLKS + NBLK, 256, 0, stream>>>(edst, dstart, dc2, dlist, sstart, bhist);
  k_sortcb2<<<NBLK + 1, 256, 0, stream>>>(dstart, dlist, bhist, boff, nchains);
  k_cbin3<<<NBLK, 256, 0, stream>>>(sstart, dstart, boff, nchains, cnode, cstart, clen, degf);
  k_lstm7<<<256, 512, 0, stream>>>(pre2b, WhhB2, cnode, cstart, clen, nchains,
                                   dlist, ctr, emb);
  k_mlp2<<<N_NODES/32, 512, 0, stream>>>(x, emb, degf, fc1wbf, fc1b, lng, lnb, outw, outb, out);
}

// Round 14
// 165.630 us; speedup vs baseline: 2.2956x; 1.0767x over previous
//
#include <hip/hip_runtime.h>
#include <math.h>

#define N_NODES 20000
#define N_EDGES 40000
#define SE 46
#define TE 82
#define NBLK 79   // ceil(N_NODES/256)
// D = 128, 4D = 512, F = 256, HID = 128

typedef short  s16x8 __attribute__((ext_vector_type(8)));
typedef short  s16x4 __attribute__((ext_vector_type(4)));
typedef float  f32x4 __attribute__((ext_vector_type(4)));

__device__ __forceinline__ float sigf(float x){ return 1.0f/(1.0f+__expf(-x)); }
__device__ __forceinline__ float tanh_f(float x){ return 1.0f - 2.0f/(__expf(2.0f*x)+1.0f); }
__device__ __forceinline__ int perm_out(int i){ return (i&3)*128 + (i>>2); }
__device__ __forceinline__ unsigned short f2bf(float f){
  unsigned u = __builtin_bit_cast(unsigned, f);
  unsigned r = (u + 0x7fff + ((u>>16)&1)) >> 16;
  return (unsigned short)r;
}
__device__ __forceinline__ float bf2f(short s){
  unsigned u = ((unsigned)(unsigned short)s) << 16;
  return __builtin_bit_cast(float, u);
}

#define GATHER_BLKS 2500
#define PREP_BLKS   704
#define HIST_BLKS   157
#define FRONT_BLKS  (GATHER_BLKS + PREP_BLKS + HIST_BLKS)

// ---------------- fused front: gather | weight-prep | hist ----------------
__global__ __launch_bounds__(256) void k_front(
    const int* __restrict__ heads, const int* __restrict__ rels,
    const int* __restrict__ tails, const float* __restrict__ weeks,
    const float* __restrict__ ent, const float* __restrict__ rel_embs,
    const float* __restrict__ wfreq, const float* __restrict__ wphi,
    const float* __restrict__ wamp, short* __restrict__ scores,
    const float* __restrict__ Wih, const float* __restrict__ Whh,
    const float* __restrict__ fc1w,
    short* __restrict__ WihB, short* __restrict__ WhhB2, short* __restrict__ fc1wbf,
    const int* __restrict__ esrc, const int* __restrict__ edst,
    int* __restrict__ scnt, int* __restrict__ dcnt){
  int blk = blockIdx.x, tid = threadIdx.x;
  if (blk < GATHER_BLKS){
    int c = blk*256 + tid;            // 640000 chunks
    int e = c >> 4, d0 = (c & 15) << 3;
    int hd = heads[e], tl = tails[e], rl = rels[e];
    float wk = weeks[e];
    float hv[8], tv[8];
    if (d0 + 8 <= SE){
      const float* hp = ent + (size_t)hd*SE + d0;
      const float* tp = ent + (size_t)tl*SE + d0;
      #pragma unroll
      for (int j=0;j<4;j++){
        float2 a = *(const float2*)(hp + j*2); hv[2*j]=a.x; hv[2*j+1]=a.y;
        float2 b = *(const float2*)(tp + j*2); tv[2*j]=b.x; tv[2*j+1]=b.y;
      }
    } else if (d0 >= 48){
      int dt = d0 - SE;
      const float *hf = wfreq + (size_t)hd*TE + dt, *hp2 = wphi + (size_t)hd*TE + dt, *ha = wamp + (size_t)hd*TE + dt;
      const float *tf = wfreq + (size_t)tl*TE + dt, *tp2 = wphi + (size_t)tl*TE + dt, *ta = wamp + (size_t)tl*TE + dt;
      #pragma unroll
      for (int j=0;j<4;j++){
        float2 f_h = *(const float2*)(hf + j*2);
        float2 p_h = *(const float2*)(hp2 + j*2);
        float2 a_h = *(const float2*)(ha + j*2);
        float2 f_t = *(const float2*)(tf + j*2);
        float2 p_t = *(const float2*)(tp2 + j*2);
        float2 a_t = *(const float2*)(ta + j*2);
        hv[2*j]   = a_h.x*__sinf(f_h.x*wk + p_h.x);
        hv[2*j+1] = a_h.y*__sinf(f_h.y*wk + p_h.y);
        tv[2*j]   = a_t.x*__sinf(f_t.x*wk + p_t.x);
        tv[2*j+1] = a_t.y*__sinf(f_t.y*wk + p_t.y);
      }
    } else {
      #pragma unroll
      for (int j=0;j<8;j++){
        int d = 40 + j;
        if (d < SE){
          hv[j] = ent[(size_t)hd*SE + d];
          tv[j] = ent[(size_t)tl*SE + d];
        } else {
          int dt = d - SE;
          hv[j] = wamp[(size_t)hd*TE+dt]*__sinf(wfreq[(size_t)hd*TE+dt]*wk + wphi[(size_t)hd*TE+dt]);
          tv[j] = wamp[(size_t)tl*TE+dt]*__sinf(wfreq[(size_t)tl*TE+dt]*wk + wphi[(size_t)tl*TE+dt]);
        }
      }
    }
    const float* rp = rel_embs + rl*128 + d0;
    float4 r0 = *(const float4*)rp, r1 = *(const float4*)(rp+4);
    float rv[8] = {r0.x,r0.y,r0.z,r0.w, r1.x,r1.y,r1.z,r1.w};
    s16x8 o;
    #pragma unroll
    for (int j=0;j<8;j++) o[j] = (short)f2bf(hv[j]*rv[j]*tv[j]);
    *(s16x8*)(scores + (size_t)e*128 + d0) = o;
  } else if (blk < GATHER_BLKS + PREP_BLKS){
    int idx = (blk - GATHER_BLKS)*256 + tid;
    if (idx < 65536){
      int i = idx >> 7, k = idx & 127;
      WihB[idx] = (short)f2bf(Wih[perm_out(i)*128 + k]);
    } else if (idx < 131072){
      int j = idx - 65536;
      WhhB2[j] = (short)f2bf(Whh[j]);
    } else if (idx < 180224){
      int j = idx - 131072;
      fc1wbf[j] = (short)f2bf(fc1w[j]);
    }
  } else {
    int e = (blk - GATHER_BLKS - PREP_BLKS)*256 + tid;
    if (e < N_EDGES){ atomicAdd(&scnt[esrc[e]],1); atomicAdd(&dcnt[edst[e]],1); }
  }
}

// ---------------- fused: scan (blocks 0,1) | MFMA pregemm (blocks 2..1251) ----------------
__global__ __launch_bounds__(256) void k_pgscan(
    const short* __restrict__ scores, const short* __restrict__ WihB,
    const float* __restrict__ bih, const float* __restrict__ bhh,
    short* __restrict__ pre2b,
    const int* __restrict__ scnt, const int* __restrict__ dcnt,
    int* __restrict__ sstart, int* __restrict__ dstart){
  __shared__ char As[32*256];   // A staging (8 KB)
  __shared__ char Bs[32*1024];  // output staging (32 KB, swizzled rows)
  __shared__ int wsA[4];
  int blk = blockIdx.x, tid = threadIdx.x;
  if (blk < 2){
    const int* cnt = blk ? dcnt : scnt;
    int* start = blk ? dstart : sstart;
    int base = tid*79;
    int lim = min(base+79, N_NODES);
    int tsum = 0;
    for (int i=base;i<lim;i++) tsum += cnt[i];
    int lane = tid & 63, wv4 = tid >> 6;
    int incl = tsum;
    #pragma unroll
    for (int m=1;m<64;m<<=1){ int u = __shfl_up(incl, m); if (lane >= m) incl += u; }
    if (lane == 63) wsA[wv4] = incl;
    __syncthreads();
    int woff = 0;
    for (int k=0;k<wv4;k++) woff += wsA[k];
    int run = woff + incl - tsum;
    for (int i=base;i<lim;i++){ start[i] = run; run += cnt[i]; }
    if (tid == 255) start[N_NODES] = run;
    return;
  }
  int e0 = (blk-2) * 32;
  #pragma unroll
  for (int q=0;q<2;q++){
    int c = tid + 256*q;            // 0..511
    int el = c >> 4, k8 = c & 15;
    s16x8 v = *(const s16x8*)(scores + (size_t)(e0+el)*128 + k8*8);
    *(s16x8*)(As + ((el*256 + k8*16) ^ ((el&7)<<4))) = v;
  }
  __syncthreads();
  int lane = tid & 63, w = tid >> 6;
  int cl = lane & 15, kq = lane >> 4;
  s16x8 a[2][4];
  #pragma unroll
  for (int ks=0;ks<4;ks++){
    int kb = ks*64 + kq*16;
    a[0][ks] = *(const s16x8*)(As + (((cl   )*256 + kb) ^ ((cl&7)<<4)));
    a[1][ks] = *(const s16x8*)(As + (((cl+16)*256 + kb) ^ (((cl+16)&7)<<4)));
  }
  f32x4 D[2][8];
  #pragma unroll
  for (int m=0;m<2;m++)
    #pragma unroll
    for (int i=0;i<8;i++) D[m][i] = (f32x4){0.f,0.f,0.f,0.f};
  #pragma unroll
  for (int i=0;i<8;i++){
    int n = w*128 + i*16 + cl;
    const short* bp = WihB + (size_t)n*128 + kq*8;
    #pragma unroll
    for (int ks=0;ks<4;ks++){
      s16x8 b = *(const s16x8*)(bp + ks*32);
      D[0][i] = __builtin_amdgcn_mfma_f32_16x16x32_bf16(a[0][ks], b, D[0][i], 0, 0, 0);
      D[1][i] = __builtin_amdgcn_mfma_f32_16x16x32_bf16(a[1][ks], b, D[1][i], 0, 0, 0);
    }
  }
  // D -> LDS bf16 (swizzled), then coalesced global write-out
  #pragma unroll
  for (int i=0;i<8;i++){
    int n = w*128 + i*16 + cl;
    int pn = perm_out(n);
    float bb = bih[pn] + bhh[pn];
    #pragma unroll
    for (int m=0;m<2;m++){
      #pragma unroll
      for (int q2=0;q2<4;q2++){
        int r = m*16 + kq*4 + q2;
        *(short*)(Bs + ((r*1024 + n*2) ^ ((r&15)<<4))) = (short)f2bf(D[m][i][q2] + bb);
      }
    }
  }
  __syncthreads();
  #pragma unroll
  for (int j=0;j<8;j++){
    int idx = j*256 + tid;          // 0..2047 16B-chunks, lane-consecutive
    int r = idx >> 6;
    int cb = (idx & 63) * 16;
    s16x8 v = *(const s16x8*)(Bs + ((r*1024 + cb) ^ ((r&15)<<4)));
    *(s16x8*)(pre2b + (size_t)e0*512 + (size_t)idx*8) = v;
  }
}

// ---------------- scatter (dst only; src list is identity) + cbin1 ----------------
__global__ __launch_bounds__(256) void k_scatcb1(
    const int* __restrict__ edst, const int* __restrict__ dstart,
    int* __restrict__ dc2, int* __restrict__ dlist,
    const int* __restrict__ sstart, int* __restrict__ bhist){
  int blk = blockIdx.x, tid = threadIdx.x;
  if (blk < HIST_BLKS){
    int e = blk*256 + tid;
    if (e < N_EDGES){
      int d = edst[e]; int p2 = dstart[d] + atomicAdd(&dc2[d],1); dlist[p2]=e;
    }
  } else {
    __shared__ int h[128];
    int b2 = blk - HIST_BLKS;
    if (tid < 128) h[tid] = 0;
    __syncthreads();
    int n = b2*256 + tid;
    if (n < N_NODES){
      int c  = sstart[n+1]-sstart[n];
      int c2 = dstart[n+1]-dstart[n];
      if (c>0 && c2==0) atomicAdd(&h[min(c,63)], 1);
      if (c2>0) atomicAdd(&h[64+min(c2,63)], 1);
    }
    __syncthreads();
    if (tid < 128) bhist[tid*NBLK + b2] = h[tid];
  }
}

__device__ __forceinline__ int mapbin(int s){
  int p = s / (63*NBLK);
  int r = s - p*(63*NBLK);
  int li = r / NBLK;
  int b  = r - li*NBLK;
  int l  = 63 - li;
  return (p*64 + l)*NBLK + b;
}

// ---------------- sort dlist groups + cbin2 (256-thread two-pass scan) ----------------
__global__ __launch_bounds__(256) void k_sortcb2(
    const int* __restrict__ dstart, int* __restrict__ dlist,
    const int* __restrict__ bhist, int* __restrict__ boff,
    int* __restrict__ nchains){
  int blk = blockIdx.x, tid = threadIdx.x;
  __shared__ int wsum[4];
  __shared__ int pend[2];
  if (blk < NBLK){
    int n = blk*256 + tid;
    if (n < N_NODES){
      int a = dstart[n], b = dstart[n+1];
      for (int i=a+1;i<b;i++){
        int v = dlist[i]; int j=i-1;
        while (j>=a && dlist[j]>v){ dlist[j+1]=dlist[j]; j--; }
        dlist[j+1]=v;
      }
    }
  } else {
    const int S = 2*63*NBLK;   // 9954
    const int CH2 = 39;        // 256*39 = 9984
    int tsum = 0;
    for (int j=0;j<CH2;j++){
      int s = tid*CH2 + j;
      if (s < S) tsum += bhist[mapbin(s)];
    }
    int lane = tid & 63, wv = tid >> 6;
    int incl = tsum;
    #pragma unroll
    for (int m=1;m<64;m<<=1){ int u = __shfl_up(incl, m); if (lane >= m) incl += u; }
    if (lane==63) wsum[wv] = incl;
    __syncthreads();
    int woff = 0;
    for (int k=0;k<wv;k++) woff += wsum[k];
    int run = woff + incl - tsum;
    for (int j=0;j<CH2;j++){
      int s = tid*CH2 + j;
      if (s < S){
        int bi = mapbin(s);
        int val = bhist[bi];
        boff[bi] = run;
        run += val;
        if (s == 63*NBLK - 1) pend[0] = run;
        if (s == S - 1)       pend[1] = run;
      }
    }
    __syncthreads();
    if (tid == 0){
      nchains[0] = pend[0];
      nchains[1] = pend[1] - pend[0];
    }
  }
}

// ---------------- cbin3: chain compaction + emb-valid flags ----------------
__global__ void k_cbin3(const int* __restrict__ sstart, const int* __restrict__ dstart,
                        const int* __restrict__ boff, const int* __restrict__ nchains,
                        int* __restrict__ cnode, int* __restrict__ cstart,
                        int* __restrict__ clen, int* __restrict__ degf){
  __shared__ int h[128];
  int tid = threadIdx.x, blk = blockIdx.x;
  if (tid < 128) h[tid] = 0;
  __syncthreads();
  int n = blk*256 + tid;
  int bin0=-1, bin1=-1, r0=0, r1=0, a0=0, c0=0, a1=0, c1=0;
  if (n < N_NODES){
    a0 = sstart[n]; c0 = sstart[n+1]-a0;
    a1 = dstart[n]; c1 = dstart[n+1]-a1;
    degf[n] = (c0+c1 > 0) ? 1 : 0;
    if (c0>0 && c1==0){ bin0 = min(c0,63);    r0 = atomicAdd(&h[bin0], 1); }
    if (c1>0)         { bin1 = 64+min(c1,63); r1 = atomicAdd(&h[bin1], 1); }
  }
  __syncthreads();
  int nch0 = nchains[0];
  if (bin0 >= 0){
    int pos = boff[bin0*NBLK + blk] + r0;
    cnode[pos] = n; cstart[pos] = a0; clen[pos] = c0;
  }
  if (bin1 >= 0){
    int pos = boff[bin1*NBLK + blk] + r1 - nch0;
    cnode[N_NODES+pos] = n; cstart[N_NODES+pos] = a1; clen[N_NODES+pos] = c1;
  }
}

// ---------------- persistent MFMA LSTM v7: Whh in registers, early eid prefetch ----------------
__global__ __launch_bounds__(512, 1) void k_lstm7(
    const short* __restrict__ pre2b, const short* __restrict__ WhhB2,
    const int* __restrict__ cnode, const int* __restrict__ cstart,
    const int* __restrict__ clen, const int* __restrict__ nchains,
    const int* __restrict__ dlist, int* __restrict__ ctr,
    float* __restrict__ emb){
  __shared__ char Hb[2][8192];
  __shared__ int M[161];
  int tid = threadIdx.x;
  int lane = tid & 63, wv = tid >> 6;
  int cl = lane & 15, kq = lane >> 4;
  int d_own = wv*16 + cl;
  s16x8 wf[4][4];
  #pragma unroll
  for (int i=0;i<4;i++)
    #pragma unroll
    for (int ks=0;ks<4;ks++)
      wf[i][ks] = *(const s16x8*)(WhhB2 + (size_t)(i*128 + d_own)*128 + ks*32 + kq*8);
  int nch0 = nchains[0], nch1 = nchains[1];
  int B0 = (nch0+31)>>5, B1 = (nch1+31)>>5;
  while (true){
    if (tid==0) M[160] = atomicAdd(ctr, 1);
    __syncthreads();
    int nb = M[160];
    if (nb >= B0 + B1) break;
    int pass = (nb >= B0) ? 1 : 0;
    int batch = pass ? nb - B0 : nb;
    int b0 = batch << 5;
    int nch = pass ? nch1 : nch0;
    if (tid < 32){
      int j = b0 + tid;
      int valid = (j < nch);
      int ci = pass*N_NODES + j;
      int st = valid ? cstart[ci] : 0;
      int ln = valid ? clen[ci] : 0;
      M[tid] = ln; M[32+tid] = st; M[128+tid] = valid ? cnode[ci] : -1;
      M[64+tid] = (ln > 0) ? (pass ? dlist[st]   : st  ) : 0;
      M[96+tid] = (ln > 1) ? (pass ? dlist[st+1] : st+1) : 0;
    }
    *(unsigned long long*)(&Hb[0][tid*16])   = 0ull;
    *(unsigned long long*)(&Hb[0][tid*16+8]) = 0ull;
    float cst[8]  = {0.f,0.f,0.f,0.f,0.f,0.f,0.f,0.f};
    float hreg[8] = {0.f,0.f,0.f,0.f,0.f,0.f,0.f,0.f};
    __syncthreads();
    int mylen[8];
    #pragma unroll
    for (int m=0;m<2;m++)
      #pragma unroll
      for (int q=0;q<4;q++) mylen[m*4+q] = M[m*16 + kq*4 + q];
    int ml = 0;
    #pragma unroll 1
    for (int j=0;j<32;j++) ml = max(ml, M[j]);
    // preload pv for t=0 (slot 0)
    s16x4 pvc[8];
    #pragma unroll
    for (int m=0;m<2;m++)
      #pragma unroll
      for (int q=0;q<4;q++){
        int r = m*16 + kq*4 + q;
        pvc[m*4+q] = *(const s16x4*)(pre2b + (size_t)M[64+r]*512 + d_own*4);
      }
    __syncthreads();   // protect slot 0 from t=0's early prefetch write
    int cur = 0;
    for (int t=0; t<ml; t++){
      // early eid prefetch for t+2 into slot (t&1) (overlaps MFMA below)
      if (tid < 32){
        int ln = M[tid];
        int nxt = M[32+tid] + t + 2;
        M[64 + ((t&1)<<5) + tid] = (t+2 < ln) ? (pass ? dlist[nxt] : nxt) : 0;
      }
      // issue pv loads for t+1 from slot ((t+1)&1)
      s16x4 pvn[8];
      const int* eidN = M + 64 + (((t+1)&1)<<5);
      #pragma unroll
      for (int m=0;m<2;m++)
        #pragma unroll
        for (int q=0;q<4;q++){
          int r = m*16 + kq*4 + q;
          pvn[m*4+q] = *(const s16x4*)(pre2b + (size_t)eidN[r]*512 + d_own*4);
        }
      // MFMA from H[cur] x wf (registers)
      f32x4 D[2][4];
      #pragma unroll
      for (int m=0;m<2;m++)
        #pragma unroll
        for (int i=0;i<4;i++) D[m][i] = (f32x4){0.f,0.f,0.f,0.f};
      char* Hc = Hb[cur];
      #pragma unroll
      for (int ks=0; ks<4; ks++){
        int kb = ks*64 + kq*16;
        s16x8 a0 = *(const s16x8*)(Hc + (((cl   )*256 + kb) ^ ((cl&7)<<4)));
        s16x8 a1 = *(const s16x8*)(Hc + (((cl+16)*256 + kb) ^ (((cl+16)&7)<<4)));
        #pragma unroll
        for (int i=0;i<4;i++){
          D[0][i] = __builtin_amdgcn_mfma_f32_16x16x32_bf16(a0, wf[i][ks], D[0][i], 0, 0, 0);
          D[1][i] = __builtin_amdgcn_mfma_f32_16x16x32_bf16(a1, wf[i][ks], D[1][i], 0, 0, 0);
        }
      }
      // gate combine with pvc; write h to H[cur^1]
      char* Hn = Hb[cur^1];
      #pragma unroll
      for (int m=0;m<2;m++)
        #pragma unroll
        for (int q=0;q<4;q++){
          int r = m*16 + kq*4 + q;
          if (t < mylen[m*4+q]){
            s16x4 p = pvc[m*4+q];
            float gi = D[m][0][q] + bf2f(p[0]);
            float gf = D[m][1][q] + bf2f(p[1]);
            float gg = D[m][2][q] + bf2f(p[2]);
            float go = D[m][3][q] + bf2f(p[3]);
            int idx = m*4+q;
            cst[idx] = sigf(gf)*cst[idx] + sigf(gi)*tanh_f(gg);
            float h = sigf(go)*tanh_f(cst[idx]);
            hreg[idx] = h;
            *(short*)(Hn + ((r*256 + d_own*2) ^ ((r&7)<<4))) = (short)f2bf(h);
          }
        }
      __syncthreads();
      #pragma unroll
      for (int i=0;i<8;i++) pvc[i] = pvn[i];
      cur ^= 1;
    }
    #pragma unroll
    for (int m=0;m<2;m++)
      #pragma unroll
      for (int q=0;q<4;q++){
        int r = m*16 + kq*4 + q;
        int n = M[128+r];
        if (mylen[m*4+q] > 0 && n >= 0){
          emb[(size_t)n*128 + d_own] = hreg[m*4+q];
        }
      }
    __syncthreads();
  }
}

// ---------------- MFMA MLP: 32 nodes/block, degf-gated emb read ----------------
__global__ __launch_bounds__(512) void k_mlp2(
    const float* __restrict__ x, const float* __restrict__ emb,
    const int* __restrict__ degf,
    const short* __restrict__ fc1wbf, const float* __restrict__ fc1b,
    const float* __restrict__ lng, const float* __restrict__ lnb,
    const float* __restrict__ outw, const float* __restrict__ outb,
    float* __restrict__ out){
  __shared__ char As[32*768];          // bf16 [32][384], XOR-swizzled rows
  __shared__ float hbuf[32][132];
  int tid = threadIdx.x;
  int lane = tid & 63, w = tid >> 6;
  int base = blockIdx.x * 32;
  #pragma unroll
  for (int q=0;q<3;q++){
    int i = tid + 512*q;              // 0..1535, 48 chunks of 8 per row
    int r = i / 48, c = i - r*48;
    s16x8 v8 = {0,0,0,0,0,0,0,0};
    if (c < 32){
      const float* src = x + (size_t)(base+r)*256 + c*8;
      float4 v0 = *(const float4*)src;
      float4 v1 = *(const float4*)(src+4);
      v8[0]=(short)f2bf(v0.x); v8[1]=(short)f2bf(v0.y); v8[2]=(short)f2bf(v0.z); v8[3]=(short)f2bf(v0.w);
      v8[4]=(short)f2bf(v1.x); v8[5]=(short)f2bf(v1.y); v8[6]=(short)f2bf(v1.z); v8[7]=(short)f2bf(v1.w);
    } else if (degf[base+r]){
      const float* src = emb + (size_t)(base+r)*128 + (c-32)*8;
      float4 v0 = *(const float4*)src;
      float4 v1 = *(const float4*)(src+4);
      v8[0]=(short)f2bf(v0.x); v8[1]=(short)f2bf(v0.y); v8[2]=(short)f2bf(v0.z); v8[3]=(short)f2bf(v0.w);
      v8[4]=(short)f2bf(v1.x); v8[5]=(short)f2bf(v1.y); v8[6]=(short)f2bf(v1.z); v8[7]=(short)f2bf(v1.w);
    }
    *(s16x8*)(As + ((r*768 + c*16) ^ ((r&7)<<4))) = v8;
  }
  __syncthreads();
  int cl = lane & 15, kq = lane >> 4;
  f32x4 D0 = {0.f,0.f,0.f,0.f}, D1 = {0.f,0.f,0.f,0.f};
  const short* bp = fc1wbf + (size_t)(w*16 + cl)*384 + kq*8;
  #pragma unroll
  for (int ks=0; ks<12; ks++){
    s16x8 b = *(const s16x8*)(bp + ks*32);
    int kb = ks*64 + kq*16;
    s16x8 a0 = *(const s16x8*)(As + (((cl   )*768 + kb) ^ ((cl&7)<<4)));
    s16x8 a1 = *(const s16x8*)(As + (((cl+16)*768 + kb) ^ (((cl+16)&7)<<4)));
    D0 = __builtin_amdgcn_mfma_f32_16x16x32_bf16(a0, b, D0, 0, 0, 0);
    D1 = __builtin_amdgcn_mfma_f32_16x16x32_bf16(a1, b, D1, 0, 0, 0);
  }
  int col = w*16 + cl;
  float bb = fc1b[col];
  #pragma unroll
  for (int q=0;q<4;q++){
    hbuf[kq*4+q][col]    = D0[q] + bb;
    hbuf[16+kq*4+q][col] = D1[q] + bb;
  }
  __syncthreads();
  int sub = lane >> 4, l16 = lane & 15;
  int nd = w*4 + sub;
  float v[8];
  float s = 0.f;
  #pragma unroll
  for (int j=0;j<8;j++){ v[j] = hbuf[nd][l16*8+j]; s += v[j]; }
  #pragma unroll
  for (int m=1;m<16;m<<=1) s += __shfl_xor(s, m);
  float mu = s * (1.f/128.f);
  float va = 0.f;
  #pragma unroll
  for (int j=0;j<8;j++){ float dm = v[j]-mu; va += dm*dm; }
  #pragma unroll
  for (int m=1;m<16;m<<=1) va += __shfl_xor(va, m);
  float rstd = rsqrtf(va*(1.f/128.f) + 1e-5f);
  float o0=0.f, o1=0.f;
  #pragma unroll
  for (int j=0;j<8;j++){
    int c = l16*8+j;
    float h1 = (v[j]-mu)*rstd*lng[c] + lnb[c];
    h1 = fmaxf(h1, 0.f);
    o0 += h1*outw[c]; o1 += h1*outw[128+c];
  }
  #pragma unroll
  for (int m=1;m<16;m<<=1){ o0 += __shfl_xor(o0,m); o1 += __shfl_xor(o1,m); }
  if (l16==0){
    out[(size_t)(base+nd)*2]   = o0 + outb[0];
    out[(size_t)(base+nd)*2+1] = o1 + outb[1];
  }
}

extern "C" void kernel_launch(void* const* d_in, const int* in_sizes, int n_in,
                              void* d_out, int out_size, void* d_ws, size_t ws_size,
                              hipStream_t stream){
  const float* x      = (const float*)d_in[0];
  const int*   heads  = (const int*)d_in[1];
  const int*   rels   = (const int*)d_in[2];
  const int*   tails  = (const int*)d_in[3];
  const float* weeks  = (const float*)d_in[4];
  const int*   esrc   = (const int*)d_in[5];
  const int*   edst   = (const int*)d_in[6];
  const float* ent    = (const float*)d_in[10];
  const float* rel_e  = (const float*)d_in[11];
  const float* wfreq  = (const float*)d_in[12];
  const float* wphi   = (const float*)d_in[13];
  const float* wamp   = (const float*)d_in[14];
  const float* Wih    = (const float*)d_in[15];
  const float* Whh    = (const float*)d_in[16];
  const float* bih    = (const float*)d_in[17];
  const float* bhh    = (const float*)d_in[18];
  const float* fc1w   = (const float*)d_in[19];
  const float* fc1b   = (const float*)d_in[20];
  const float* lng    = (const float*)d_in[21];
  const float* lnb    = (const float*)d_in[22];
  const float* outw   = (const float*)d_in[23];
  const float* outb   = (const float*)d_in[24];
  float* out = (float*)d_out;

  char* ws = (char*)d_ws;
  size_t off = 0;
  auto alloc = [&](size_t bytes){ void* p = ws + off; off += (bytes + 255) & ~(size_t)255; return p; };
  short* pre2b  = (short*)alloc((size_t)N_EDGES*512*2);
  short* scores = (short*)alloc((size_t)N_EDGES*128*2);
  short* WihB   = (short*)alloc(512*128*2);
  short* WhhB2  = (short*)alloc(512*128*2);
  short* fc1wbf = (short*)alloc(128*384*2);
  float* emb    = (float*)alloc((size_t)N_NODES*128*4);
  int* sstart   = (int*)alloc((N_NODES+1)*4);
  int* dstart   = (int*)alloc((N_NODES+1)*4);
  int* zreg     = (int*)alloc((size_t)(3*N_NODES + 3)*4);
  int* scnt = zreg, *dcnt = zreg+N_NODES, *dc2 = zreg+2*N_NODES;
  int* nchains  = zreg + 3*N_NODES;
  int* ctr      = nchains + 2;
  int* bhist    = (int*)alloc((size_t)128*NBLK*4);
  int* boff     = (int*)alloc((size_t)128*NBLK*4);
  int* dlist    = (int*)alloc(N_EDGES*4);
  int* cnode    = (int*)alloc((size_t)2*N_NODES*4);
  int* cstart   = (int*)alloc((size_t)2*N_NODES*4);
  int* clen     = (int*)alloc((size_t)2*N_NODES*4);
  int* degf     = (int*)alloc((size_t)N_NODES*4);

  hipMemsetAsync(zreg, 0, (size_t)(3*N_NODES + 3)*4, stream);

  k_front<<<FRONT_BLKS, 256, 0, stream>>>(heads, rels, tails, weeks, ent, rel_e,
                                          wfreq, wphi, wamp, scores,
                                          Wih, Whh, fc1w, WihB, WhhB2, fc1wbf,
                                          esrc, edst, scnt, dcnt);
  k_pgscan<<<2 + N_EDGES/32, 256, 0, stream>>>(scores, WihB, bih, bhh, pre2b,
                                               scnt, dcnt, sstart, dstart);
  k_scatcb1<<<HIST_BLKS + NBLK, 256, 0, stream>>>(edst, dstart, dc2, dlist, sstart, bhist);
  k_sortcb2<<<NBLK + 1, 256, 0, stream>>>(dstart, dlist, bhist, boff, nchains);
  k_cbin3<<<NBLK, 256, 0, stream>>>(sstart, dstart, boff, nchains, cnode, cstart, clen, degf);
  k_lstm7<<<256, 512, 0, stream>>>(pre2b, WhhB2, cnode, cstart, clen, nchains,
                                   dlist, ctr, emb);
  k_mlp2<<<N_NODES/32, 512, 0, stream>>>(x, emb, degf, fc1wbf, fc1b, lng, lnb, outw, outb, out);
}